// Round 1
// baseline (52585.455 us; speedup 1.0000x reference)
//
#include <hip/hip_runtime.h>
#include <math.h>

static constexpr int T_STEPS = 10000;
static constexpr int I_DIM = 2048;
static constexpr int O_DIM = 512;
static constexpr int KMAX = 192;          // max spikes/step tracked (mean 102.4, sigma 9.9 -> +9 sigma)
static constexpr float PSPD = 0.9512294245007140091f;  // exp(-0.001/0.02)
static constexpr float OUTD = 0.9048374180359595732f;  // exp(-0.001/0.01)
static constexpr float MU = 0.1f;

// ---------------- K1: compress spikes into ordered index lists ----------------
__global__ void build_idx_kernel(const float* __restrict__ spikes,
                                 unsigned short* __restrict__ idxl,
                                 int* __restrict__ cnts) {
    int t = blockIdx.x;
    int tid = threadIdx.x;                 // 256 threads
    const float4* row = reinterpret_cast<const float4*>(spikes + (size_t)t * I_DIM);
    float4 a = row[tid * 2];
    float4 b = row[tid * 2 + 1];
    float v[8] = {a.x, a.y, a.z, a.w, b.x, b.y, b.z, b.w};
    unsigned short tmp[8];
    int c = 0;
#pragma unroll
    for (int j = 0; j < 8; ++j)
        if (v[j] != 0.0f) tmp[c++] = (unsigned short)(tid * 8 + j);

    // ordered (deterministic) compaction: wave-level inclusive scan + wave offsets
    int lane = tid & 63, wid = tid >> 6;
    int x = c;
    for (int d = 1; d < 64; d <<= 1) {
        int y = __shfl_up(x, d);
        if (lane >= d) x += y;
    }
    __shared__ int wtot[4];
    if (lane == 63) wtot[wid] = x;
    __syncthreads();
    int off = x - c;
    for (int w = 0; w < wid; ++w) off += wtot[w];
    for (int j = 0; j < c; ++j) {
        int p = off + j;
        if (p < KMAX) idxl[(size_t)t * KMAX + p] = tmp[j];
    }
    if (tid == 0) {
        int tot = wtot[0] + wtot[1] + wtot[2] + wtot[3];
        cnts[t] = tot > KMAX ? KMAX : tot;
    }
}

// ---------------- K2a: copy W into mutable row-major workspace ----------------
__global__ void copy_w_kernel(const float* __restrict__ W, float* __restrict__ Wrow) {
    int i = blockIdx.x * blockDim.x + threadIdx.x;   // over float4s: 262144
    reinterpret_cast<float4*>(Wrow)[i] = reinterpret_cast<const float4*>(W)[i];
}

// ---------------- K2b: tiled transpose W[O][I] -> Wt[I][O] ----------------
__global__ void transpose_kernel(const float* __restrict__ W, float* __restrict__ Wt) {
    __shared__ float tile[32][33];
    int i0 = blockIdx.x * 32;   // input-dim tile
    int o0 = blockIdx.y * 32;   // output-dim tile
    int x = threadIdx.x;        // 0..31
    for (int y = threadIdx.y; y < 32; y += 8)
        tile[y][x] = W[(size_t)(o0 + y) * I_DIM + i0 + x];
    __syncthreads();
    for (int y = threadIdx.y; y < 32; y += 8)
        Wt[(size_t)(i0 + y) * O_DIM + o0 + x] = tile[x][y];
}

__device__ __forceinline__ void f4add(float4& a, const float4& b) {
    a.x += b.x; a.y += b.y; a.z += b.z; a.w += b.w;
}

// ---------------- K3: the sequential 10000-step loop (one workgroup) ----------------
__launch_bounds__(1024)
__global__ void seq_kernel(const unsigned short* __restrict__ idxl,
                           const int* __restrict__ cnts,
                           const float* __restrict__ u_rand,
                           const float* __restrict__ b_in,
                           float* __restrict__ Wrow,
                           float* __restrict__ Wt,
                           float* __restrict__ out) {
    __shared__ float psp[I_DIM];            // 8 KB
    __shared__ float4 sg[8][128];           // 16 KB gather partials
    __shared__ float A[O_DIM];              // W @ psp (incremental)
    __shared__ float bb[O_DIM];
    __shared__ float tr[O_DIM];
    __shared__ float redA[8];               // wave maxes
    __shared__ float redB[8];               // wave sums of e
    __shared__ float redC[8];               // wave totals of p (prefix)
    __shared__ int   redD[8];               // wave counts (cumsum < u)
    __shared__ float redE[16];              // dot-correction partials
    __shared__ unsigned short sidx[KMAX];
    __shared__ int s_r;

    const int tid = threadIdx.x;            // 1024 threads = 16 waves
    const int lane = tid & 63;
    const int widx = tid >> 6;              // 0..15
    const int g = tid & 127;                // float4 group within a Wt row
    const int jsp = tid >> 7;               // 0..7 split-K lane
    const float4* Wt4 = reinterpret_cast<const float4*>(Wt);
    const float* sgf = reinterpret_cast<const float*>(sg);

    // init state
    psp[tid] = 0.0f;
    psp[tid + 1024] = 0.0f;
    if (tid < O_DIM) { A[tid] = 0.0f; tr[tid] = 0.0f; bb[tid] = b_in[tid]; }
    __syncthreads();

    for (int t = 0; t < T_STEPS; ++t) {
        // ---- P1: stage indices, decay psp & trace ----
        const int cnt = cnts[t];            // uniform broadcast load
        const float u = u_rand[t];
        if (tid < KMAX) sidx[tid] = idxl[(size_t)t * KMAX + tid];
        psp[tid] *= PSPD;
        psp[tid + 1024] *= PSPD;
        if (tid < O_DIM) tr[tid] *= OUTD;
        __syncthreads();                    // B1

        // ---- P2: spike adds + sparse column gather (W @ s_t) ----
        if (tid < cnt) psp[sidx[tid]] += 1.0f;
        float4 acc = {0.0f, 0.0f, 0.0f, 0.0f};
        int k = jsp;
        for (; k + 24 < cnt; k += 32) {
            float4 a0 = Wt4[(int)sidx[k] * 128 + g];
            float4 a1 = Wt4[(int)sidx[k + 8] * 128 + g];
            float4 a2 = Wt4[(int)sidx[k + 16] * 128 + g];
            float4 a3 = Wt4[(int)sidx[k + 24] * 128 + g];
            f4add(acc, a0); f4add(acc, a1); f4add(acc, a2); f4add(acc, a3);
        }
        for (; k < cnt; k += 8) {
            float4 a0 = Wt4[(int)sidx[k] * 128 + g];
            f4add(acc, a0);
        }
        sg[jsp][g] = acc;
        __syncthreads();                    // B2

        // ---- P3: combine, A update, z, softmax max ----
        float z = 0.0f, e = 0.0f, x = 0.0f;
        if (tid < O_DIM) {
            float val = sgf[tid];
#pragma unroll
            for (int j = 1; j < 8; ++j) val += sgf[j * 512 + tid];
            float a = PSPD * A[tid] + val;
            A[tid] = a;
            z = a + bb[tid];
            float wm = z;
            for (int d = 32; d; d >>= 1) wm = fmaxf(wm, __shfl_xor(wm, d));
            if (lane == 0) redA[widx] = wm;
        }
        __syncthreads();                    // B3

        if (tid < O_DIM) {
            float m = redA[0];
#pragma unroll
            for (int w = 1; w < 8; ++w) m = fmaxf(m, redA[w]);
            e = expf(z - m);
            float ws = e;
            for (int d = 32; d; d >>= 1) ws += __shfl_xor(ws, d);
            if (lane == 0) redB[widx] = ws;
        }
        __syncthreads();                    // B4

        if (tid < O_DIM) {
            float S = redB[0];
#pragma unroll
            for (int w = 1; w < 8; ++w) S += redB[w];
            float p = e / S;
            x = p;
            for (int d = 1; d < 64; d <<= 1) {
                float y = __shfl_up(x, d);
                if (lane >= d) x += y;
            }
            if (lane == 63) redC[widx] = x;
        }
        __syncthreads();                    // B5

        if (tid < O_DIM) {
            float offt = 0.0f;
            for (int w = 0; w < widx; ++w) offt += redC[w];
            float cp = x + offt;
            unsigned long long bal = __ballot(cp < u);
            if (lane == 0) redD[widx] = (int)__popcll(bal);
        }
        __syncthreads();                    // B6

        if (tid == 0) {
            int idx = redD[0];
#pragma unroll
            for (int w = 1; w < 8; ++w) idx += redD[w];
            if (idx > O_DIM - 1) idx = O_DIM - 1;
            s_r = idx;
            tr[idx] += 1.0f;
            float bo = bb[idx];
            bb[idx] = bo + MU * (expf(-bo) - 1.0f);
            out[(size_t)t * O_DIM + idx] = 1.0f;
        }
        __syncthreads();                    // B7

        // ---- P4: STDP row update (winning row, dense over I) ----
        const int rr = s_r;
        const int i2 = tid * 2;
        float2 w2 = *reinterpret_cast<float2*>(&Wrow[(size_t)rr * I_DIM + i2]);
        float p0 = psp[i2], p1 = psp[i2 + 1];
        float nw0 = w2.x + MU * (expf(-w2.x) * p0 - 1.0f);
        float nw1 = w2.y + MU * (expf(-w2.y) * p1 - 1.0f);
        *reinterpret_cast<float2*>(&Wrow[(size_t)rr * I_DIM + i2]) = make_float2(nw0, nw1);
        Wt[(size_t)i2 * O_DIM + rr] = nw0;
        Wt[(size_t)(i2 + 1) * O_DIM + rr] = nw1;
        float dpart = (nw0 - w2.x) * p0 + (nw1 - w2.y) * p1;
        for (int d = 32; d; d >>= 1) dpart += __shfl_xor(dpart, d);
        if (lane == 0) redE[widx] = dpart;
        __syncthreads();                    // B8

        if (tid == 0) {
            float D = redE[0];
#pragma unroll
            for (int w = 1; w < 16; ++w) D += redE[w];
            A[rr] += D;                     // keep A == W_new @ psp exactly (algebraically)
        }
        // next iteration's B1/B2 order this write before any A read
    }

    __syncthreads();
    if (tid < O_DIM) out[(size_t)T_STEPS * O_DIM + tid] = tr[tid];
}

extern "C" void kernel_launch(void* const* d_in, const int* in_sizes, int n_in,
                              void* d_out, int out_size, void* d_ws, size_t ws_size,
                              hipStream_t stream) {
    const float* spikes = (const float*)d_in[0];   // [T, I]
    const float* u_rand = (const float*)d_in[1];   // [T]
    const float* W      = (const float*)d_in[2];   // [O, I]
    const float* b      = (const float*)d_in[3];   // [O]
    float* out = (float*)d_out;                    // [T*O + O]

    float* Wrow = (float*)d_ws;                                   // 4 MB
    float* Wt   = Wrow + (size_t)O_DIM * I_DIM;                   // 4 MB
    unsigned short* idxl = (unsigned short*)(Wt + (size_t)O_DIM * I_DIM); // 3.84 MB
    int* cnts = (int*)(idxl + (size_t)T_STEPS * KMAX);            // 40 KB

    // zero the one-hot output (only winners get written)
    hipMemsetAsync(d_out, 0, (size_t)out_size * sizeof(float), stream);

    hipLaunchKernelGGL(build_idx_kernel, dim3(T_STEPS), dim3(256), 0, stream,
                       spikes, idxl, cnts);
    hipLaunchKernelGGL(copy_w_kernel, dim3((O_DIM * I_DIM / 4) / 256), dim3(256), 0, stream,
                       W, Wrow);
    hipLaunchKernelGGL(transpose_kernel, dim3(I_DIM / 32, O_DIM / 32), dim3(32, 8), 0, stream,
                       W, Wt);
    hipLaunchKernelGGL(seq_kernel, dim3(1), dim3(1024), 0, stream,
                       idxl, cnts, u_rand, b, Wrow, Wt, out);
}

// Round 2
// 52186.792 us; speedup vs baseline: 1.0076x; 1.0076x over previous
//
#include <hip/hip_runtime.h>
#include <math.h>

static constexpr int T_STEPS = 10000;
static constexpr int I_DIM = 2048;
static constexpr int O_DIM = 512;
static constexpr int KMAX = 176;          // max spikes/step (mean 102.4, sd 9.9 -> +7.5 sigma)
static constexpr int GN = 16;             // fixed gather loads/thread (covers k<128; tail path beyond)
static constexpr float PSPD = 0.9512294245007140091f;  // exp(-0.001/0.02)
static constexpr float OUTD = 0.9048374180359595732f;  // exp(-0.001/0.01)
static constexpr float MU = 0.1f;

// ---------------- K1: compress spikes into ordered, PADDED index lists ----------------
// pad value = I_DIM -> points at an all-zero row of Wt, so fixed-count gathers add +0.0
__global__ void build_idx_kernel(const float* __restrict__ spikes,
                                 unsigned short* __restrict__ idxl,
                                 int* __restrict__ cnts) {
    int t = blockIdx.x;
    int tid = threadIdx.x;                 // 256 threads
    if (t == T_STEPS) {                    // extra pad row for step T (staged but unused)
        for (int p = tid; p < KMAX; p += 256) idxl[(size_t)t * KMAX + p] = (unsigned short)I_DIM;
        if (tid == 0) cnts[t] = 0;
        return;
    }
    const float4* row = reinterpret_cast<const float4*>(spikes + (size_t)t * I_DIM);
    float4 a = row[tid * 2];
    float4 b = row[tid * 2 + 1];
    float v[8] = {a.x, a.y, a.z, a.w, b.x, b.y, b.z, b.w};
    unsigned short tmp[8];
    int c = 0;
#pragma unroll
    for (int j = 0; j < 8; ++j)
        if (v[j] != 0.0f) tmp[c++] = (unsigned short)(tid * 8 + j);

    int lane = tid & 63, wid = tid >> 6;
    int x = c;
    for (int d = 1; d < 64; d <<= 1) {
        int y = __shfl_up(x, d);
        if (lane >= d) x += y;
    }
    __shared__ int wtot[4];
    if (lane == 63) wtot[wid] = x;
    __syncthreads();
    int off = x - c;
    for (int w = 0; w < wid; ++w) off += wtot[w];
    int tot = wtot[0] + wtot[1] + wtot[2] + wtot[3];
    if (tot > KMAX) tot = KMAX;
    for (int j = 0; j < c; ++j) {
        int p = off + j;
        if (p < KMAX) idxl[(size_t)t * KMAX + p] = tmp[j];
    }
    for (int p = tid; p < KMAX; p += 256)
        if (p >= tot) idxl[(size_t)t * KMAX + p] = (unsigned short)I_DIM;
    if (tid == 0) cnts[t] = tot;
}

// ---------------- K2a: copy W into mutable row-major workspace ----------------
__global__ void copy_w_kernel(const float* __restrict__ W, float* __restrict__ Wrow) {
    int i = blockIdx.x * blockDim.x + threadIdx.x;
    reinterpret_cast<float4*>(Wrow)[i] = reinterpret_cast<const float4*>(W)[i];
}

// ---------------- K2b: tiled transpose W[O][I] -> Wt[I][O] ----------------
__global__ void transpose_kernel(const float* __restrict__ W, float* __restrict__ Wt) {
    __shared__ float tile[32][33];
    int i0 = blockIdx.x * 32;
    int o0 = blockIdx.y * 32;
    int x = threadIdx.x;
    for (int y = threadIdx.y; y < 32; y += 8)
        tile[y][x] = W[(size_t)(o0 + y) * I_DIM + i0 + x];
    __syncthreads();
    for (int y = threadIdx.y; y < 32; y += 8)
        Wt[(size_t)(i0 + y) * O_DIM + o0 + x] = tile[x][y];
}

// ---------------- K2c: zero the pad row of Wt (row index I_DIM) ----------------
__global__ void zero_pad_row_kernel(float* __restrict__ Wt) {
    Wt[(size_t)I_DIM * O_DIM + threadIdx.x + blockIdx.x * 256] = 0.0f;
}

__device__ __forceinline__ void f4add(float4& a, const float4& b) {
    a.x += b.x; a.y += b.y; a.z += b.z; a.w += b.w;
}

// raw barrier: LDS-drain only; does NOT drain vmcnt, so global loads stay in flight
__device__ __forceinline__ void bar() {
    asm volatile("s_waitcnt lgkmcnt(0)" ::: "memory");
    __builtin_amdgcn_sched_barrier(0);
    __builtin_amdgcn_s_barrier();
    __builtin_amdgcn_sched_barrier(0);
}

// ---------------- K3: the sequential 10000-step loop (one workgroup) ----------------
__launch_bounds__(1024, 1)
__global__ void seq_kernel(const unsigned short* __restrict__ idxl,
                           const int* __restrict__ cnts,
                           const float* __restrict__ u_rand,
                           const float* __restrict__ b_in,
                           float* __restrict__ Wrow,
                           float* __restrict__ Wt,
                           float* __restrict__ out) {
    __shared__ float psp[I_DIM + 2];        // pad slot for scattered pad writes
    __shared__ float spk[I_DIM + 2];        // dense spike mask of step t+1
    __shared__ float4 sg[8][128];           // gather partials (split-K)
    __shared__ float A[O_DIM];              // incremental W @ psp
    __shared__ float bb[O_DIM];
    __shared__ float tr[O_DIM];
    __shared__ float redA[8], redB[8], redC[8];
    __shared__ int   redD[8];
    __shared__ float redE[16], redF[16];
    __shared__ unsigned short sidx[2][KMAX];
    __shared__ float s_corrG;

    const int tid = threadIdx.x;            // 1024 threads = 16 waves
    const int lane = tid & 63;
    const int widx = tid >> 6;
    const int g = tid & 127;                // float4 group within a Wt row
    const int jsp = tid >> 7;               // 0..7 split-K lane
    const float4* __restrict__ Wt4 = reinterpret_cast<const float4*>(Wt);
    const float* sgf = reinterpret_cast<const float*>(sg);

    // ---------------- prologue ----------------
    psp[tid] = 0.0f; psp[tid + 1024] = 0.0f;
    spk[tid] = 0.0f; spk[tid + 1024] = 0.0f;
    if (tid < 2) { psp[I_DIM + tid] = 0.0f; spk[I_DIM + tid] = 0.0f; }
    if (tid < O_DIM) { A[tid] = 0.0f; tr[tid] = 0.0f; bb[tid] = b_in[tid]; }
    if (tid < KMAX) {
        sidx[1][tid] = idxl[tid];            // indices of step 0
        sidx[0][tid] = idxl[KMAX + tid];     // indices of step 1
    }
    if (tid == 0) s_corrG = 0.0f;
    __syncthreads();
    const int cnt0 = cnts[0];
    if (tid < cnt0) psp[sidx[1][tid]] += 1.0f;   // psp(0) = s_0 exactly
    __syncthreads();
    {   // synchronous gather of G(0) = W @ s_0
        float4 acc = {0.0f, 0.0f, 0.0f, 0.0f};
        for (int k = jsp; k < 128; k += 8) {
            int col = __builtin_amdgcn_readfirstlane((int)sidx[1][k]);
            f4add(acc, Wt4[(size_t)col * 128 + g]);
        }
        for (int k = 128 + jsp; k < cnt0; k += 8) {
            int col = __builtin_amdgcn_readfirstlane((int)sidx[1][k]);
            f4add(acc, Wt4[(size_t)col * 128 + g]);
        }
        sg[jsp][g] = acc;
    }
    int rprev = -1;
    int cnt_nxt = cnts[1];
    float u = u_rand[0];
    __syncthreads();

    for (int t = 0; t < T_STEPS; ++t) {
        const int par = t & 1;

        // ---- Ph1: spike mask for t+1, issue gathers for t+1, combine G(t), wave max ----
        if (tid < KMAX) spk[sidx[par][tid]] = 1.0f;   // pads hit spk[I_DIM] (harmless)
        int cols[GN];
#pragma unroll
        for (int j = 0; j < GN; ++j) cols[j] = (int)sidx[par][jsp + 8 * j];
        float4 vals[GN];
#pragma unroll
        for (int j = 0; j < GN; ++j) {
            int col = __builtin_amdgcn_readfirstlane(cols[j]);
            vals[j] = Wt4[(size_t)col * 128 + g];     // consumed in Ph5; stays in flight
        }
        if (tid < O_DIM) tr[tid] *= OUTD;
        float z = 0.0f, e = 0.0f, x = 0.0f;
        if (tid < O_DIM) {
            float val = sgf[tid];
#pragma unroll
            for (int j = 1; j < 8; ++j) val += sgf[j * 512 + tid];
            if (tid == rprev) val = s_corrG;          // exact fix of the one stale entry
            float a = PSPD * A[tid] + val;
            A[tid] = a;
            z = a + bb[tid];
            float wm = z;
            for (int d = 32; d; d >>= 1) wm = fmaxf(wm, __shfl_xor(wm, d));
            if (lane == 0) redA[widx] = wm;
        }
        bar();  // B1

        // ---- Ph2: global max, e, wave sum ----
        if (tid < O_DIM) {
            float m = redA[0];
#pragma unroll
            for (int w = 1; w < 8; ++w) m = fmaxf(m, redA[w]);
            e = expf(z - m);
            float ws = e;
            for (int d = 32; d; d >>= 1) ws += __shfl_xor(ws, d);
            if (lane == 0) redB[widx] = ws;
        }
        bar();  // B2

        // ---- Ph3: S, p, wave prefix ----
        if (tid < O_DIM) {
            float S = redB[0];
#pragma unroll
            for (int w = 1; w < 8; ++w) S += redB[w];
            float p = e / S;
            x = p;
            for (int d = 1; d < 64; d <<= 1) {
                float y = __shfl_up(x, d);
                if (lane >= d) x += y;
            }
            if (lane == 63) redC[widx] = x;
        }
        bar();  // B3

        // ---- Ph4: global prefix offset + ballot counts ----
        if (tid < O_DIM) {
            float offt = 0.0f;
            for (int w = 0; w < widx; ++w) offt += redC[w];
            float cp = x + offt;
            unsigned long long balm = __ballot(cp < u);
            if (lane == 0) redD[widx] = (int)__popcll(balm);
        }
        bar();  // B4

        // ---- Ph5: winner (all threads), row update, gather consume ----
        int rr;
        {
            int idxs = redD[0];
#pragma unroll
            for (int w = 1; w < 8; ++w) idxs += redD[w];
            rr = idxs > O_DIM - 1 ? O_DIM - 1 : idxs;
        }
        const int i2 = tid * 2;
        float2 w2 = *reinterpret_cast<const float2*>(&Wrow[(size_t)rr * I_DIM + i2]);
        if (tid == 0) {
            tr[rr] += 1.0f;
            float bo = bb[rr];
            bb[rr] = bo + MU * (expf(-bo) - 1.0f);
            out[(size_t)t * O_DIM + rr] = 1.0f;
        }
        {   // consume the in-flight gathers (k ascending => same rounding as before)
            float4 acc = vals[0];
#pragma unroll
            for (int j = 1; j < GN; ++j) f4add(acc, vals[j]);
            if (cnt_nxt > 8 * GN) {
                for (int k = 8 * GN + jsp; k < cnt_nxt; k += 8) {
                    int col = __builtin_amdgcn_readfirstlane((int)sidx[par][k]);
                    f4add(acc, Wt4[(size_t)col * 128 + g]);
                }
            }
            sg[jsp][g] = acc;
        }
        // STDP row update (winning row, dense over I), using psp(t)
        float p0 = psp[i2], p1 = psp[i2 + 1];
        float nw0 = w2.x + MU * (expf(-w2.x) * p0 - 1.0f);
        float nw1 = w2.y + MU * (expf(-w2.y) * p1 - 1.0f);
        *reinterpret_cast<float2*>(&Wrow[(size_t)rr * I_DIM + i2]) = make_float2(nw0, nw1);
        Wt[(size_t)i2 * O_DIM + rr] = nw0;
        Wt[(size_t)(i2 + 1) * O_DIM + rr] = nw1;
        float dpart = (nw0 - w2.x) * p0 + (nw1 - w2.y) * p1;   // A[rr] correction
        float gpart = nw0 * spk[i2] + nw1 * spk[i2 + 1];       // G(t+1)[rr] exact value
        for (int d = 32; d; d >>= 1) {
            dpart += __shfl_xor(dpart, d);
            gpart += __shfl_xor(gpart, d);
        }
        if (lane == 0) { redE[widx] = dpart; redF[widx] = gpart; }
        rprev = rr;
        asm volatile("s_waitcnt vmcnt(0)" ::: "memory");  // commit Wrow/Wt stores before B5
        bar();  // B5

        // ---- Ph6: finalize corrections, advance psp, clear spk, stage t+2 ----
        if (tid == 0) {
            float D = redE[0];
#pragma unroll
            for (int w = 1; w < 16; ++w) D += redE[w];
            A[rr] += D;
            float CG = redF[0];
#pragma unroll
            for (int w = 1; w < 16; ++w) CG += redF[w];
            s_corrG = CG;
        }
        {
#pragma clang fp contract(off)
            float v0 = psp[tid] * PSPD;        v0 += spk[tid];        psp[tid] = v0;
            float v1 = psp[tid + 1024] * PSPD; v1 += spk[tid + 1024]; psp[tid + 1024] = v1;
        }
        spk[tid] = 0.0f; spk[tid + 1024] = 0.0f;
        if (tid == 0) spk[I_DIM] = 0.0f;
        {
            int ts = t + 2; if (ts > T_STEPS) ts = T_STEPS;
            if (tid < KMAX) sidx[par ^ 1][tid] = idxl[(size_t)ts * KMAX + tid];
            cnt_nxt = cnts[ts];
            int tu = t + 1; if (tu > T_STEPS - 1) tu = T_STEPS - 1;
            u = u_rand[tu];
        }
        bar();  // B6
    }

    __syncthreads();
    if (tid < O_DIM) out[(size_t)T_STEPS * O_DIM + tid] = tr[tid];
}

extern "C" void kernel_launch(void* const* d_in, const int* in_sizes, int n_in,
                              void* d_out, int out_size, void* d_ws, size_t ws_size,
                              hipStream_t stream) {
    const float* spikes = (const float*)d_in[0];   // [T, I]
    const float* u_rand = (const float*)d_in[1];   // [T]
    const float* W      = (const float*)d_in[2];   // [O, I]
    const float* b      = (const float*)d_in[3];   // [O]
    float* out = (float*)d_out;                    // [T*O + O]

    float* Wrow = (float*)d_ws;                                        // 4 MB
    float* Wt   = Wrow + (size_t)O_DIM * I_DIM;                        // (I+1) x O = ~4.2 MB
    unsigned short* idxl = (unsigned short*)(Wt + (size_t)(I_DIM + 1) * O_DIM);
    int* cnts = (int*)(idxl + (size_t)(T_STEPS + 1) * KMAX);

    hipMemsetAsync(d_out, 0, (size_t)out_size * sizeof(float), stream);

    hipLaunchKernelGGL(build_idx_kernel, dim3(T_STEPS + 1), dim3(256), 0, stream,
                       spikes, idxl, cnts);
    hipLaunchKernelGGL(copy_w_kernel, dim3((O_DIM * I_DIM / 4) / 256), dim3(256), 0, stream,
                       W, Wrow);
    hipLaunchKernelGGL(transpose_kernel, dim3(I_DIM / 32, O_DIM / 32), dim3(32, 8), 0, stream,
                       W, Wt);
    hipLaunchKernelGGL(zero_pad_row_kernel, dim3(O_DIM / 256), dim3(256), 0, stream, Wt);
    hipLaunchKernelGGL(seq_kernel, dim3(1), dim3(1024), 0, stream,
                       idxl, cnts, u_rand, b, Wrow, Wt, out);
}

// Round 3
// 50625.223 us; speedup vs baseline: 1.0387x; 1.0308x over previous
//
#include <hip/hip_runtime.h>
#include <math.h>

static constexpr int T_STEPS = 10000;
static constexpr int I_DIM = 2048;
static constexpr int O_DIM = 512;
static constexpr int KPAD = 192;          // padded spike list (mean 102.4, sd 9.9)
static constexpr int GN = 16;             // fixed async gather loads/thread (covers cnt<=128)
static constexpr float PSPD = 0.9512294245007140091f;  // exp(-0.001/0.02)
static constexpr float OUTD = 0.9048374180359595732f;  // exp(-0.001/0.01)
static constexpr float MU = 0.1f;

typedef float __attribute__((ext_vector_type(4))) f32x4;

// ---------------- K1: compress spikes into ordered, PADDED index lists ----------------
__global__ void build_idx_kernel(const float* __restrict__ spikes,
                                 unsigned short* __restrict__ idxl,
                                 int* __restrict__ cnts) {
    int t = blockIdx.x;
    int tid = threadIdx.x;                 // 256 threads
    if (t >= T_STEPS) {                    // pad rows t = T, T+1
        for (int p = tid; p < KPAD; p += 256) idxl[(size_t)t * KPAD + p] = (unsigned short)I_DIM;
        if (tid == 0) cnts[t] = 0;
        return;
    }
    const float4* row = reinterpret_cast<const float4*>(spikes + (size_t)t * I_DIM);
    float4 a = row[tid * 2];
    float4 b = row[tid * 2 + 1];
    float v[8] = {a.x, a.y, a.z, a.w, b.x, b.y, b.z, b.w};
    unsigned short tmp[8];
    int c = 0;
#pragma unroll
    for (int j = 0; j < 8; ++j)
        if (v[j] != 0.0f) tmp[c++] = (unsigned short)(tid * 8 + j);

    int lane = tid & 63, wid = tid >> 6;
    int x = c;
    for (int d = 1; d < 64; d <<= 1) {
        int y = __shfl_up(x, d);
        if (lane >= d) x += y;
    }
    __shared__ int wtot[4];
    if (lane == 63) wtot[wid] = x;
    __syncthreads();
    int off = x - c;
    for (int w = 0; w < wid; ++w) off += wtot[w];
    int tot = wtot[0] + wtot[1] + wtot[2] + wtot[3];
    if (tot > KPAD) tot = KPAD;
    for (int j = 0; j < c; ++j) {
        int p = off + j;
        if (p < KPAD) idxl[(size_t)t * KPAD + p] = tmp[j];
    }
    for (int p = tid; p < KPAD; p += 256)
        if (p >= tot) idxl[(size_t)t * KPAD + p] = (unsigned short)I_DIM;
    if (tid == 0) cnts[t] = tot;
}

// ---------------- K2a: copy W into mutable row-major workspace ----------------
__global__ void copy_w_kernel(const float* __restrict__ W, float* __restrict__ Wrow) {
    int i = blockIdx.x * blockDim.x + threadIdx.x;
    reinterpret_cast<float4*>(Wrow)[i] = reinterpret_cast<const float4*>(W)[i];
}

// ---------------- K2b: tiled transpose W[O][I] -> Wt[I][O] ----------------
__global__ void transpose_kernel(const float* __restrict__ W, float* __restrict__ Wt) {
    __shared__ float tile[32][33];
    int i0 = blockIdx.x * 32;
    int o0 = blockIdx.y * 32;
    int x = threadIdx.x;
    for (int y = threadIdx.y; y < 32; y += 8)
        tile[y][x] = W[(size_t)(o0 + y) * I_DIM + i0 + x];
    __syncthreads();
    for (int y = threadIdx.y; y < 32; y += 8)
        Wt[(size_t)(i0 + y) * O_DIM + o0 + x] = tile[x][y];
}

// ---------------- K2c: zero the pad row of Wt (row index I_DIM) ----------------
__global__ void zero_pad_row_kernel(float* __restrict__ Wt) {
    Wt[(size_t)I_DIM * O_DIM + threadIdx.x + blockIdx.x * 256] = 0.0f;
}

// light barrier: LDS-drain only; global loads stay in flight
__device__ __forceinline__ void bar() {
    asm volatile("s_waitcnt lgkmcnt(0)" ::: "memory");
    __builtin_amdgcn_sched_barrier(0);
    __builtin_amdgcn_s_barrier();
    __builtin_amdgcn_sched_barrier(0);
}

// exact wave64 max via DPP scan (max is associative: tree change is bitwise-safe)
__device__ __forceinline__ float wave_max_dpp(float x) {
    int xb = __float_as_int(x);
#define DPPSTEP(ctrl, rm)                                                        \
    {                                                                            \
        int tt = __builtin_amdgcn_update_dpp(0xff800000, xb, ctrl, rm, 0xf, false); \
        xb = __float_as_int(fmaxf(__int_as_float(xb), __int_as_float(tt)));      \
    }
    DPPSTEP(0x111, 0xf)   // row_shr:1
    DPPSTEP(0x112, 0xf)   // row_shr:2
    DPPSTEP(0x114, 0xf)   // row_shr:4
    DPPSTEP(0x118, 0xf)   // row_shr:8
    DPPSTEP(0x142, 0xa)   // row_bcast:15 -> rows 1,3
    DPPSTEP(0x143, 0xc)   // row_bcast:31 -> rows 2,3
#undef DPPSTEP
    return __int_as_float(__builtin_amdgcn_readlane(xb, 63));
}

// ---------------- K3: the sequential 10000-step loop (one workgroup) ----------------
__launch_bounds__(1024, 1)
__global__ void seq_kernel(const unsigned short* __restrict__ idxl,
                           const int* __restrict__ cnts,
                           const float* __restrict__ u_rand,
                           const float* __restrict__ b_in,
                           float* __restrict__ Wrow,
                           float* __restrict__ Wt,
                           float* __restrict__ out) {
    __shared__ float psp[I_DIM + 2];
    __shared__ float spk[I_DIM + 2];
    __shared__ f32x4 sg[8][128];            // gather partials (split-K)
    __shared__ float A[O_DIM];
    __shared__ float bb[O_DIM];
    __shared__ float tr[O_DIM];
    __shared__ float redA[8], redB[8], redC[8];
    __shared__ float redE[16], redF[16];
    __shared__ unsigned short sidx[2][KPAD];
    __shared__ int s_rr;

    const int tid = threadIdx.x;            // 1024 threads = 16 waves
    const int lane = tid & 63;
    const int widx = tid >> 6;
    const int g = tid & 127;
    const int jsp = tid >> 7;               // 0..7, wave-uniform
    const f32x4* __restrict__ Wt4 = reinterpret_cast<const f32x4*>(Wt);
    const float* sgf = reinterpret_cast<const float*>(sg);

    // ---------------- prologue ----------------
    psp[tid] = 0.0f; psp[tid + 1024] = 0.0f;
    spk[tid] = 0.0f; spk[tid + 1024] = 0.0f;
    if (tid < 2) { psp[I_DIM + tid] = 0.0f; spk[I_DIM + tid] = 0.0f; }
    if (tid < O_DIM) { A[tid] = 0.0f; tr[tid] = 0.0f; bb[tid] = b_in[tid]; }
    if (tid < KPAD) {
        sidx[0][tid] = idxl[(size_t)KPAD + tid];   // row 1 (for Ph_A(0))
        sidx[1][tid] = idxl[tid];                  // row 0 (prologue gather)
    }
    __syncthreads();
    const int cnt0 = cnts[0];
    if (tid < cnt0) psp[sidx[1][tid]] = 1.0f;      // psp(0) = s_0
    __syncthreads();
    {   // synchronous gather of G(0) = W0 @ s_0
        f32x4 acc = {0.0f, 0.0f, 0.0f, 0.0f};
        for (int k = jsp; k < cnt0; k += 8) {
            int col = (int)sidx[1][k];
            acc += Wt4[(size_t)col * 128 + g];
        }
        sg[jsp][g] = acc;
    }
    int rprev = 0x40000000;
    int cnt_use = cnts[1];
    float u_cur = u_rand[0];
    __syncthreads();

    for (int t = 0; t < T_STEPS; ++t) {
        const int par = t & 1;

        // ================= Ph_A =================
        // async prefetches for t+1 / t+2 (forced via asm; drained in Ph_E)
        float u_nxt;
        {
            const float* up = u_rand + (t + 1 < T_STEPS ? t + 1 : T_STEPS - 1);
            asm volatile("global_load_dword %0, %1, off" : "=&v"(u_nxt) : "v"(up) : "memory");
        }
        int cnt_fut;
        {
            const int* cp2 = cnts + (t + 2);
            asm volatile("global_load_dword %0, %1, off" : "=&v"(cnt_fut) : "v"(cp2) : "memory");
        }
        unsigned int pfw = 0;
        if (tid >= 512 && tid < 512 + KPAD / 2) {
            const unsigned int* pp = reinterpret_cast<const unsigned int*>(idxl) +
                                     (size_t)(t + 2) * (KPAD / 2) + (tid - 512);
            asm volatile("global_load_dword %0, %1, off" : "=&v"(pfw) : "v"(pp) : "memory");
        }
        // spike mask for t+1
        if (tid < cnt_use) spk[sidx[par][tid]] = 1.0f;
        // async gather issue for G(t+1) (reads W as committed through step t-1)
        f32x4 vals[GN];
#pragma unroll
        for (int j = 0; j < GN; ++j) {
            int col = (int)sidx[par][jsp + 8 * j];
            const f32x4* p = Wt4 + (size_t)col * 128 + g;
            asm volatile("global_load_dwordx4 %0, %1, off" : "=&v"(vals[j]) : "v"(p) : "memory");
        }
        if (tid < O_DIM) tr[tid] *= OUTD;
        // combine G(t) + corrections, z, wave max
        float z = 0.0f, e = 0.0f, x = 0.0f;
        if (tid < O_DIM) {
            float val = sgf[tid];
#pragma unroll
            for (int j = 1; j < 8; ++j) val += sgf[j * 512 + tid];
            if (tid == rprev) {
                float D = redE[0];
#pragma unroll
                for (int w = 1; w < 16; ++w) D += redE[w];
                A[tid] += D;                       // A[rr] fix: Drow . psp(t-1)
                float CG = redF[0];
#pragma unroll
                for (int w = 1; w < 16; ++w) CG += redF[w];
                val = CG;                          // exact replacement of stale entry
            }
            float a = PSPD * A[tid] + val;
            A[tid] = a;
            z = a + bb[tid];
            float wm = wave_max_dpp(z);
            if (lane == 0) redA[widx] = wm;
        }
        bar();  // B1

        // ================= Ph_B: global max, e, wave sum =================
        if (tid < O_DIM) {
            float m = redA[0];
#pragma unroll
            for (int w = 1; w < 8; ++w) m = fmaxf(m, redA[w]);
            e = expf(z - m);
            float ws = e;
            for (int d = 32; d; d >>= 1) ws += __shfl_xor(ws, d);
            if (lane == 0) redB[widx] = ws;
        }
        bar();  // B2

        // ================= Ph_C: S, p, wave prefix =================
        if (tid < O_DIM) {
            float S = redB[0];
#pragma unroll
            for (int w = 1; w < 8; ++w) S += redB[w];
            float p = e / S;
            x = p;
            for (int d = 1; d < 64; d <<= 1) {
                float y = __shfl_up(x, d);
                if (lane >= d) x += y;
            }
            if (lane == 63) redC[widx] = x;
        }
        bar();  // B3

        // ================= Ph_D: winner detect (no ballot phase) =================
        if (tid < O_DIM) {
            float offt = 0.0f;
            for (int w = 0; w < widx; ++w) offt += redC[w];
            float cp = x + offt;
            float xp = __shfl_up(x, 1);
            float cpprev = (lane == 0) ? offt : (xp + offt);
            // winner o: cumsum_{o-1} < u <= cumsum_o ; fallback: all below -> 511
            bool win = (cp >= u_cur && cpprev < u_cur) || (tid == O_DIM - 1 && cp < u_cur);
            if (win) s_rr = tid;
        }
        bar();  // B4

        // ================= Ph_E: consume gather, row update, psp advance =================
        const int rr = s_rr;
        // drain ALL async loads issued in Ph_A (gather + u/cnt/idx prefetch)
        asm volatile("s_waitcnt vmcnt(0)" ::: "memory");
        __builtin_amdgcn_sched_barrier(0);
        asm volatile("" : "+v"(cnt_fut), "+v"(u_nxt));   // pin post-drain values
        {
            f32x4 acc = vals[0];
#pragma unroll
            for (int j = 1; j < GN; ++j) acc += vals[j];
            if (cnt_use > 8 * GN) {                      // rare tail (cnt > 128)
                for (int k = 8 * GN + jsp; k < cnt_use; k += 8) {
                    int col = (int)sidx[par][k];
                    acc += Wt4[(size_t)col * 128 + g];
                }
            }
            sg[jsp][g] = acc;
        }
        const int i2 = tid * 2;
        float2 w2 = *reinterpret_cast<const float2*>(&Wrow[(size_t)rr * I_DIM + i2]);
        if (tid == rr) {
            tr[rr] += 1.0f;
            float bo = bb[rr];
            bb[rr] = bo + MU * (expf(-bo) - 1.0f);
            out[(size_t)t * O_DIM + rr] = 1.0f;
        }
        float p0 = psp[i2], p1 = psp[i2 + 1];
        float s0 = spk[i2], s1 = spk[i2 + 1];
        float nw0 = w2.x + MU * (expf(-w2.x) * p0 - 1.0f);
        float nw1 = w2.y + MU * (expf(-w2.y) * p1 - 1.0f);
        *reinterpret_cast<float2*>(&Wrow[(size_t)rr * I_DIM + i2]) = make_float2(nw0, nw1);
        Wt[(size_t)i2 * O_DIM + rr] = nw0;
        Wt[(size_t)(i2 + 1) * O_DIM + rr] = nw1;
        float dpart = (nw0 - w2.x) * p0 + (nw1 - w2.y) * p1;   // A[rr] correction
        float gpart = nw0 * s0 + nw1 * s1;                     // G(t+1)[rr] exact value
        for (int d = 32; d; d >>= 1) {
            dpart += __shfl_xor(dpart, d);
            gpart += __shfl_xor(gpart, d);
        }
        if (lane == 0) { redE[widx] = dpart; redF[widx] = gpart; }
        // psp advance + spk clear (same-thread indices: no intra-phase race)
        {
#pragma clang fp contract(off)
            float v0 = p0 * PSPD; v0 += s0; psp[i2] = v0;
            float v1 = p1 * PSPD; v1 += s1; psp[i2 + 1] = v1;
        }
        spk[i2] = 0.0f; spk[i2 + 1] = 0.0f;
        // stage t+2 index list into the buffer Ph_A(t+1) reads
        if (tid >= 512 && tid < 512 + KPAD / 2)
            reinterpret_cast<unsigned int*>(&sidx[par ^ 1][0])[tid - 512] = pfw;
        rprev = rr;
        cnt_use = cnt_fut;
        u_cur = u_nxt;
        asm volatile("s_waitcnt vmcnt(0)" ::: "memory");  // commit Wrow/Wt stores
        bar();  // B5
    }

    __syncthreads();
    if (tid < O_DIM) out[(size_t)T_STEPS * O_DIM + tid] = tr[tid];
}

extern "C" void kernel_launch(void* const* d_in, const int* in_sizes, int n_in,
                              void* d_out, int out_size, void* d_ws, size_t ws_size,
                              hipStream_t stream) {
    const float* spikes = (const float*)d_in[0];   // [T, I]
    const float* u_rand = (const float*)d_in[1];   // [T]
    const float* W      = (const float*)d_in[2];   // [O, I]
    const float* b      = (const float*)d_in[3];   // [O]
    float* out = (float*)d_out;                    // [T*O + O]

    float* Wrow = (float*)d_ws;                                        // 4 MB
    float* Wt   = Wrow + (size_t)O_DIM * I_DIM;                        // (I+1) x O
    unsigned short* idxl = (unsigned short*)(Wt + (size_t)(I_DIM + 1) * O_DIM);
    int* cnts = (int*)(idxl + (size_t)(T_STEPS + 2) * KPAD);

    hipMemsetAsync(d_out, 0, (size_t)out_size * sizeof(float), stream);

    hipLaunchKernelGGL(build_idx_kernel, dim3(T_STEPS + 2), dim3(256), 0, stream,
                       spikes, idxl, cnts);
    hipLaunchKernelGGL(copy_w_kernel, dim3((O_DIM * I_DIM / 4) / 256), dim3(256), 0, stream,
                       W, Wrow);
    hipLaunchKernelGGL(transpose_kernel, dim3(I_DIM / 32, O_DIM / 32), dim3(32, 8), 0, stream,
                       W, Wt);
    hipLaunchKernelGGL(zero_pad_row_kernel, dim3(O_DIM / 256), dim3(256), 0, stream, Wt);
    hipLaunchKernelGGL(seq_kernel, dim3(1), dim3(1024), 0, stream,
                       idxl, cnts, u_rand, b, Wrow, Wt, out);
}

// Round 4
// 40029.462 us; speedup vs baseline: 1.3137x; 1.2647x over previous
//
#include <hip/hip_runtime.h>
#include <math.h>

static constexpr int T_STEPS = 10000;
static constexpr int I_DIM = 2048;
static constexpr int O_DIM = 512;
static constexpr int KPAD = 192;          // padded spike list (mean 102.4, sd 9.9)
static constexpr int GN = 16;             // fixed async gather loads/thread (covers cnt<=128)
static constexpr float PSPD = 0.9512294245007140091f;  // exp(-0.001/0.02)
static constexpr float OUTD = 0.9048374180359595732f;  // exp(-0.001/0.01)
static constexpr float MU = 0.1f;

typedef float __attribute__((ext_vector_type(4))) f32x4;
typedef float __attribute__((ext_vector_type(2))) f32x2;

// ---------------- K1: compress spikes into ordered, PADDED index lists ----------------
__global__ void build_idx_kernel(const float* __restrict__ spikes,
                                 unsigned short* __restrict__ idxl,
                                 int* __restrict__ cnts) {
    int t = blockIdx.x;
    int tid = threadIdx.x;                 // 256 threads
    if (t >= T_STEPS) {                    // pad rows t = T, T+1
        for (int p = tid; p < KPAD; p += 256) idxl[(size_t)t * KPAD + p] = (unsigned short)I_DIM;
        if (tid == 0) cnts[t] = 0;
        return;
    }
    const float4* row = reinterpret_cast<const float4*>(spikes + (size_t)t * I_DIM);
    float4 a = row[tid * 2];
    float4 b = row[tid * 2 + 1];
    float v[8] = {a.x, a.y, a.z, a.w, b.x, b.y, b.z, b.w};
    unsigned short tmp[8];
    int c = 0;
#pragma unroll
    for (int j = 0; j < 8; ++j)
        if (v[j] != 0.0f) tmp[c++] = (unsigned short)(tid * 8 + j);

    int lane = tid & 63, wid = tid >> 6;
    int x = c;
    for (int d = 1; d < 64; d <<= 1) {
        int y = __shfl_up(x, d);
        if (lane >= d) x += y;
    }
    __shared__ int wtot[4];
    if (lane == 63) wtot[wid] = x;
    __syncthreads();
    int off = x - c;
    for (int w = 0; w < wid; ++w) off += wtot[w];
    int tot = wtot[0] + wtot[1] + wtot[2] + wtot[3];
    if (tot > KPAD) tot = KPAD;
    for (int j = 0; j < c; ++j) {
        int p = off + j;
        if (p < KPAD) idxl[(size_t)t * KPAD + p] = tmp[j];
    }
    for (int p = tid; p < KPAD; p += 256)
        if (p >= tot) idxl[(size_t)t * KPAD + p] = (unsigned short)I_DIM;
    if (tid == 0) cnts[t] = tot;
}

// ---------------- K2a: copy W into mutable row-major workspace ----------------
__global__ void copy_w_kernel(const float* __restrict__ W, float* __restrict__ Wrow) {
    int i = blockIdx.x * blockDim.x + threadIdx.x;
    reinterpret_cast<float4*>(Wrow)[i] = reinterpret_cast<const float4*>(W)[i];
}

// ---------------- K2b: tiled transpose W[O][I] -> Wt[I][O] ----------------
__global__ void transpose_kernel(const float* __restrict__ W, float* __restrict__ Wt) {
    __shared__ float tile[32][33];
    int i0 = blockIdx.x * 32;
    int o0 = blockIdx.y * 32;
    int x = threadIdx.x;
    for (int y = threadIdx.y; y < 32; y += 8)
        tile[y][x] = W[(size_t)(o0 + y) * I_DIM + i0 + x];
    __syncthreads();
    for (int y = threadIdx.y; y < 32; y += 8)
        Wt[(size_t)(i0 + y) * O_DIM + o0 + x] = tile[x][y];
}

// ---------------- K2c: zero the pad row of Wt (row index I_DIM) ----------------
__global__ void zero_pad_row_kernel(float* __restrict__ Wt) {
    Wt[(size_t)I_DIM * O_DIM + threadIdx.x + blockIdx.x * 256] = 0.0f;
}

// light barrier: LDS-drain only; global loads stay in flight
__device__ __forceinline__ void bar() {
    asm volatile("s_waitcnt lgkmcnt(0)" ::: "memory");
    __builtin_amdgcn_sched_barrier(0);
    __builtin_amdgcn_s_barrier();
    __builtin_amdgcn_sched_barrier(0);
}

// wave64 max, uniform result (max associative -> any tree bitwise-safe)
__device__ __forceinline__ float wave_max_dpp(float x) {
    int xb = __float_as_int(x);
#define DPPSTEPM(ctrl, rm)                                                          \
    {                                                                               \
        int tt = __builtin_amdgcn_update_dpp(0xff800000, xb, ctrl, rm, 0xf, false); \
        xb = __float_as_int(fmaxf(__int_as_float(xb), __int_as_float(tt)));         \
    }
    DPPSTEPM(0x111, 0xf)
    DPPSTEPM(0x112, 0xf)
    DPPSTEPM(0x114, 0xf)
    DPPSTEPM(0x118, 0xf)
    DPPSTEPM(0x142, 0xa)
    DPPSTEPM(0x143, 0xc)
#undef DPPSTEPM
    return __int_as_float(__builtin_amdgcn_readlane(xb, 63));
}

// wave64 inclusive prefix sum (per-lane); lane63 = wave total
__device__ __forceinline__ float dpp_scan_add(float x) {
#define DPPSTEPA(ctrl, rm)                                                          \
    {                                                                               \
        float tt = __int_as_float(                                                  \
            __builtin_amdgcn_update_dpp(0, __float_as_int(x), ctrl, rm, 0xf, false)); \
        x += tt;                                                                    \
    }
    DPPSTEPA(0x111, 0xf)
    DPPSTEPA(0x112, 0xf)
    DPPSTEPA(0x114, 0xf)
    DPPSTEPA(0x118, 0xf)
    DPPSTEPA(0x142, 0xa)
    DPPSTEPA(0x143, 0xc)
#undef DPPSTEPA
    return x;
}

// ---------------- K3: the sequential 10000-step loop (one workgroup) ----------------
__launch_bounds__(1024, 1)
__global__ void seq_kernel(const unsigned short* __restrict__ idxl,
                           const int* __restrict__ cnts,
                           const float* __restrict__ u_rand,
                           const float* __restrict__ b_in,
                           float* __restrict__ Wrow,
                           float* __restrict__ Wt,
                           float* __restrict__ out) {
    __shared__ float psp[I_DIM + 2];
    __shared__ float mask0[I_DIM + 2];      // spike masks, double buffered by step parity
    __shared__ float mask1[I_DIM + 2];
    __shared__ f32x4 sg[8 * 128];           // gather partials (split-K)
    __shared__ float A[O_DIM];
    __shared__ float bb[O_DIM];
    __shared__ float tr[O_DIM];
    __shared__ float redA[8], redB[8];
    __shared__ float redE[16], redF[16], redG[2][16];
    __shared__ uint4 sidxq[2][KPAD / 8];    // 2 index lists, 16B-aligned
    __shared__ int s_rr;

    const int tid = threadIdx.x;            // 1024 threads = 16 waves
    const int lane = tid & 63;
    const int widx = tid >> 6;
    const int g = tid & 127;
    const int jsp = tid >> 7;               // 0..7, wave-pair uniform
    const int i2 = tid * 2;
    const f32x4* __restrict__ Wt4 = reinterpret_cast<const f32x4*>(Wt);
    const float* sgf = reinterpret_cast<const float*>(sg);
    const unsigned long long wt_base = (unsigned long long)Wt;

    // ---------------- prologue ----------------
    psp[tid] = 0.0f; psp[tid + 1024] = 0.0f;
    mask0[tid] = 0.0f; mask0[tid + 1024] = 0.0f;
    mask1[tid] = 0.0f; mask1[tid + 1024] = 0.0f;
    if (tid < 2) { psp[I_DIM + tid] = 0.0f; mask0[I_DIM + tid] = 0.0f; mask1[I_DIM + tid] = 0.0f; }
    if (tid < O_DIM) { A[tid] = 0.0f; tr[tid] = 0.0f; bb[tid] = b_in[tid]; }
    if (tid < KPAD) {
        ((unsigned short*)sidxq[0])[tid] = idxl[tid];           // list 0 (prologue only)
        ((unsigned short*)sidxq[1])[tid] = idxl[KPAD + tid];    // list 1
    }
    if (tid == 0) s_rr = O_DIM;
    __syncthreads();
    const int cnt0 = cnts[0];
    if (tid < KPAD) {
        int i0 = ((const unsigned short*)sidxq[0])[tid];
        psp[i0] = 1.0f;                     // psp(0) = s_0 (pads hit dead slot)
        int i1 = ((const unsigned short*)sidxq[1])[tid];
        mask1[i1] = 1.0f;                   // mask of s_1
    }
    __syncthreads();
    {   // synchronous gather of G(0) = W0 @ s_0  (same order as main loop)
        const unsigned short* l0 = (const unsigned short*)sidxq[0];
        f32x4 acc = {0.0f, 0.0f, 0.0f, 0.0f};
        for (int k = jsp; k < cnt0; k += 8) {
            int col = l0[k];
            acc += Wt4[(size_t)col * 128 + g];
        }
        sg[jsp * 128 + g] = acc;
    }
    int rprev1 = 0x40000000, rprev2 = 0x40000000;
    int cnt_use = cnts[1];
    float u_cur = u_rand[0];
    float nw0 = 0.0f, nw1 = 0.0f;           // persisted winning-row values
    __syncthreads();

    for (int t = 0; t < T_STEPS; ++t) {
        const int par = t & 1;
        float* mcur = par ? mask1 : mask0;  // cleared now; E scatters s_{t+2} here
        float* mnxt = par ? mask0 : mask1;  // holds s_{t+1}

        // ================= Phase A =================
        // async prefetches for t+1/t+2 (drained in Phase E)
        float u_nxt; int cnt_fut;
        {
            const float* up = u_rand + (t + 1 < T_STEPS ? t + 1 : T_STEPS - 1);
            asm volatile("global_load_dword %0, %1, off" : "=&v"(u_nxt) : "v"(up) : "memory");
            const int* cp = cnts + (t + 2);
            asm volatile("global_load_dword %0, %1, off" : "=&v"(cnt_fut) : "v"(cp) : "memory");
        }
        unsigned int pfw = 0;
        if (tid >= 512 && tid < 512 + KPAD / 2) {
            const unsigned int* pp = reinterpret_cast<const unsigned int*>(idxl) +
                                     (size_t)(t + 2) * (KPAD / 2) + (tid - 512);
            asm volatile("global_load_dword %0, %1, off" : "=&v"(pfw) : "v"(pp) : "memory");
        }
        // async gather issue for G(t+1): columns k = jsp + 8j (same order as R3)
        f32x4 vals[GN];
        {
            const unsigned int* lst32 = (const unsigned int*)sidxq[par ^ 1];
            const unsigned int half = (jsp & 1) * 16;
            const int bdw = jsp >> 1;
#pragma unroll
            for (int j = 0; j < GN; ++j) {
                unsigned int dw = lst32[bdw + 4 * j];
                unsigned int col = (dw >> half) & 0xffffu;
                unsigned int voff = (col << 11) + ((unsigned)g << 4);
                asm volatile("global_load_dwordx4 %0, %1, %2"
                             : "=&v"(vals[j]) : "v"(voff), "s"(wt_base) : "memory");
            }
        }
        // gpart2(t-1) = W_{t-1}[rr(t-1)] . s_{t+1}  (for 2-deep stale correction)
        float m0v = mnxt[i2], m1v = mnxt[i2 + 1];
        {
            float gp2 = nw0 * m0v + nw1 * m1v;
            float gs = dpp_scan_add(gp2);
            if (lane == 63) redG[par][widx] = gs;
        }
        // clear mcur (own slots); reset winner slot
        mcur[i2] = 0.0f; mcur[i2 + 1] = 0.0f;
        if (tid == 0) s_rr = O_DIM;
        if (tid < O_DIM) tr[tid] *= OUTD;
        // combine G(t) + corrections, z, in-wave softmax pieces
        float z = 0.0f, e = 0.0f, pe = 0.0f, m_w = 0.0f;
        if (tid < O_DIM) {
            float val = sgf[tid];
#pragma unroll
            for (int j = 1; j < 8; ++j) val += sgf[j * 512 + tid];
            if (tid == rprev1) {
                float D = redE[0];
#pragma unroll
                for (int w = 1; w < 16; ++w) D += redE[w];
                A[tid] += D;                // A[rr] fix: Drow . psp(t-1)
                float CF = redF[0];
#pragma unroll
                for (int w = 1; w < 16; ++w) CF += redF[w];
                val = CF;                   // exact replacement: W_{t-1}[rr1] . s_t
            } else if (tid == rprev2) {
                float CG = redG[par ^ 1][0];
#pragma unroll
                for (int w = 1; w < 16; ++w) CG += redG[par ^ 1][w];
                val = CG;                   // exact replacement: W_{t-2}[rr2] . s_t
            }
            float a = PSPD * A[tid] + val;
            A[tid] = a;
            z = a + bb[tid];
            m_w = wave_max_dpp(z);
            e = expf(z - m_w);
            pe = dpp_scan_add(e);           // inclusive prefix; lane63 = wave sum
            if (lane == 63) { redA[widx] = m_w; redB[widx] = pe; }
        }
        bar();  // B1

        // ================= Phase B: global softmax + winner =================
        if (tid < O_DIM) {
            float mj[8], sj[8];
#pragma unroll
            for (int j = 0; j < 8; ++j) { mj[j] = redA[j]; sj[j] = redB[j]; }
            float M = mj[0];
#pragma unroll
            for (int j = 1; j < 8; ++j) M = fmaxf(M, mj[j]);
            float o_run = 0.0f, offw = 0.0f, myscale = 0.0f;
#pragma unroll
            for (int j = 0; j < 8; ++j) {
                float sc = expf(mj[j] - M);
                if (j == widx) { offw = o_run; myscale = sc; }
                o_run = fmaf(sj[j], sc, o_run);
            }
            float uQ = u_cur * o_run;       // compare in numerator space (no divide)
            // exact exclusive prefix (bitwise neighbor copy)
            float ex = __int_as_float(
                __builtin_amdgcn_update_dpp(0, __float_as_int(pe), 0x111, 0xf, 0xf, false));
            float p15 = __int_as_float(__builtin_amdgcn_readlane(__float_as_int(pe), 15));
            float p31 = __int_as_float(__builtin_amdgcn_readlane(__float_as_int(pe), 31));
            float p47 = __int_as_float(__builtin_amdgcn_readlane(__float_as_int(pe), 47));
            if (lane == 16) ex = p15;
            if (lane == 32) ex = p31;
            if (lane == 48) ex = p47;
            float cq  = fmaf(pe, myscale, offw);
            float cqp = fmaf(ex, myscale, offw);
            bool win = (cqp < uQ) && (cq >= uQ || tid == O_DIM - 1);
            if (win) atomicMin(&s_rr, tid);
        }
        bar();  // B2

        // ================= Phase E: consume gather, row update, psp advance =================
        int rr = s_rr;
        if (rr > O_DIM - 1) rr = O_DIM - 1;
        // issue winning-row load before the drain (latency hides under gather stall)
        f32x2 w2;
        {
            const float* rp = Wrow + (size_t)rr * I_DIM + i2;
            asm volatile("global_load_dwordx2 %0, %1, off" : "=&v"(w2) : "v"(rp) : "memory");
        }
        asm volatile("s_waitcnt vmcnt(0)" ::: "memory");   // gathers + prefetches + row
        __builtin_amdgcn_sched_barrier(0);
        // stage list t+2 + scatter mask s_{t+2} (direct from prefetch regs)
        if (tid >= 512 && tid < 512 + KPAD / 2) {
            ((unsigned int*)sidxq[par])[tid - 512] = pfw;
            int ia = pfw & 0xffffu, ib = pfw >> 16;
            mcur[ia] = 1.0f;
            mcur[ib] = 1.0f;
        }
        // consume gather (ascending k: bitwise same as sync version)
        {
            f32x4 acc = vals[0];
#pragma unroll
            for (int j = 1; j < GN; ++j) acc += vals[j];
            if (cnt_use > 8 * GN) {                        // rare tail (cnt > 128)
                const unsigned short* lst = (const unsigned short*)sidxq[par ^ 1];
                for (int k = 8 * GN + jsp; k < cnt_use; k += 8) {
                    int col = lst[k];
                    acc += Wt4[(size_t)col * 128 + g];
                }
            }
            sg[jsp * 128 + g] = acc;
        }
        // STDP row update with psp(t); s0/s1 = s_{t+1} mask (regs from Phase A)
        float p0 = psp[i2], p1 = psp[i2 + 1];
        float s0 = m0v, s1 = m1v;
        nw0 = w2.x + MU * (expf(-w2.x) * p0 - 1.0f);
        nw1 = w2.y + MU * (expf(-w2.y) * p1 - 1.0f);
        *reinterpret_cast<float2*>(&Wrow[(size_t)rr * I_DIM + i2]) = make_float2(nw0, nw1);
        Wt[(size_t)i2 * O_DIM + rr] = nw0;
        Wt[(size_t)(i2 + 1) * O_DIM + rr] = nw1;
        float dpart = (nw0 - w2.x) * p0 + (nw1 - w2.y) * p1;   // A[rr] correction
        float gpart = nw0 * s0 + nw1 * s1;                     // G(t+1)[rr] exact value
        {
            float ds = dpp_scan_add(dpart);
            float gs = dpp_scan_add(gpart);
            if (lane == 63) { redE[widx] = ds; redF[widx] = gs; }
        }
        // psp advance (exact same arithmetic form as before)
        {
#pragma clang fp contract(off)
            float v0 = p0 * PSPD; v0 += s0; psp[i2] = v0;
            float v1 = p1 * PSPD; v1 += s1; psp[i2 + 1] = v1;
        }
        if (tid == rr) {
            tr[rr] += 1.0f;
            float bo = bb[rr];
            bb[rr] = bo + MU * (expf(-bo) - 1.0f);
            out[(size_t)t * O_DIM + rr] = 1.0f;
        }
        rprev2 = rprev1;
        rprev1 = rr;
        cnt_use = cnt_fut;
        u_cur = u_nxt;
        bar();  // B3
    }

    __syncthreads();
    if (tid < O_DIM) out[(size_t)T_STEPS * O_DIM + tid] = tr[tid];
}

extern "C" void kernel_launch(void* const* d_in, const int* in_sizes, int n_in,
                              void* d_out, int out_size, void* d_ws, size_t ws_size,
                              hipStream_t stream) {
    const float* spikes = (const float*)d_in[0];   // [T, I]
    const float* u_rand = (const float*)d_in[1];   // [T]
    const float* W      = (const float*)d_in[2];   // [O, I]
    const float* b      = (const float*)d_in[3];   // [O]
    float* out = (float*)d_out;                    // [T*O + O]

    float* Wrow = (float*)d_ws;                                        // 4 MB
    float* Wt   = Wrow + (size_t)O_DIM * I_DIM;                        // (I+1) x O
    unsigned short* idxl = (unsigned short*)(Wt + (size_t)(I_DIM + 1) * O_DIM);
    int* cnts = (int*)(idxl + (size_t)(T_STEPS + 2) * KPAD);

    hipMemsetAsync(d_out, 0, (size_t)out_size * sizeof(float), stream);

    hipLaunchKernelGGL(build_idx_kernel, dim3(T_STEPS + 2), dim3(256), 0, stream,
                       spikes, idxl, cnts);
    hipLaunchKernelGGL(copy_w_kernel, dim3((O_DIM * I_DIM / 4) / 256), dim3(256), 0, stream,
                       W, Wrow);
    hipLaunchKernelGGL(transpose_kernel, dim3(I_DIM / 32, O_DIM / 32), dim3(32, 8), 0, stream,
                       W, Wt);
    hipLaunchKernelGGL(zero_pad_row_kernel, dim3(O_DIM / 256), dim3(256), 0, stream, Wt);
    hipLaunchKernelGGL(seq_kernel, dim3(1), dim3(1024), 0, stream,
                       idxl, cnts, u_rand, b, Wrow, Wt, out);
}